// Round 8
// baseline (5083.146 us; speedup 1.0000x reference)
//
#include <hip/hip_runtime.h>
#include <stdint.h>

typedef __attribute__((ext_vector_type(8))) short short8;
typedef __attribute__((ext_vector_type(4))) float floatx4;
typedef unsigned short u16;
typedef unsigned int u32;

constexpr int BSZ = 64;     // batch
constexpr int SEQT = 512;   // encoder timesteps
constexpr int FIN = 64;     // input features F
constexpr int HID = 512;    // hidden H
constexpr int NG = 2048;    // 4*H gate rows
constexpr int FUTL = 96;    // decoder steps
constexpr int K0 = FIN + HID;   // 576
constexpr int K1 = HID + HID;   // 1024
constexpr int K0P = K0 + 8;     // padded LDS row stride for layer-0 W
constexpr int NGRP = 256;       // layer-group blocks (2 groups x 128)
constexpr int NFCB = 4;         // dedicated fc blocks (off critical path)
constexpr int NBLK = NGRP + NFCB;
constexpr int NTHR = 256;

// packed activation slabs: one slab = 4 cols x 64 batch x u32(hi|lo<<16) = 1KB
constexpr int SLOT_HP = 128 * 256;  // u32 per h slot (128 slabs)
constexpr int SLOT_XP = 16 * 256;   // u32 per x slot (16 slabs)
constexpr int NSLOT_H = 65;         // slot 0 = zeros; slot(u) = u%64+1

// ---------------- workspace layout (bytes) ----------------
constexpr size_t S_W0 = (size_t)NG * K0 * 2;
constexpr size_t S_W1 = (size_t)NG * K1 * 2;
constexpr size_t S_FC = (size_t)FIN * HID * 2;

constexpr size_t OFF_WHI_E0 = 0;
constexpr size_t OFF_WLO_E0 = OFF_WHI_E0 + S_W0;
constexpr size_t OFF_WHI_E1 = OFF_WLO_E0 + S_W0;
constexpr size_t OFF_WLO_E1 = OFF_WHI_E1 + S_W1;
constexpr size_t OFF_WHI_D1 = OFF_WLO_E1 + S_W1;
constexpr size_t OFF_WLO_D1 = OFF_WHI_D1 + S_W1;
constexpr size_t OFF_WFH   = OFF_WLO_D1 + S_W1;  // fused dec-L0 [2048][1024] = [Wih0d@fcW | Whh0d]
constexpr size_t OFF_WFL   = OFF_WFH + S_W1;
constexpr size_t OFF_FCHI  = OFF_WFL + S_W1;
constexpr size_t OFF_FCLO  = OFF_FCHI + S_FC;
constexpr size_t OFF_GX    = OFF_FCLO + S_FC;               // [2048][64] f32: Wih0d@(x_last - fcb)
constexpr size_t OFF_BEFF  = OFF_GX + (size_t)NG * BSZ * 4; // [2048] f32: bdih0+bdhh0+Wih0d@fcb
constexpr size_t OFF_XP    = OFF_BEFF + (size_t)NG * 4;     // 512 slots
constexpr size_t OFF_H0P   = OFF_XP + (size_t)SEQT * SLOT_XP * 4;
constexpr size_t OFF_H1P   = OFF_H0P + (size_t)NSLOT_H * SLOT_HP * 4;
constexpr size_t OFF_CNT   = OFF_H1P + (size_t)NSLOT_H * SLOT_HP * 4;
constexpr size_t CNT_BYTES = 65536;

// cnt layout (u32 idx): fcdone @0 (4 cells x16); done0 @256 (128x16); done1 @2304;
// goA0 @4352; goB0 @6400; goA1 @8448; goB1 @10496.
#define FCF(c)   ((c) + 0)
#define DONE0(c) ((c) + 256)
#define DONE1(c) ((c) + 2304)
#define GOA0(c)  ((c) + 4352)
#define GOB0(c)  ((c) + 6400)
#define GOA1(c)  ((c) + 8448)
#define GOB1(c)  ((c) + 10496)

// ---------------- bf16 helpers ----------------
__device__ __forceinline__ u16 f2bf(float f) {
  u32 u = __float_as_uint(f);
  u += 0x7FFFu + ((u >> 16) & 1u);   // RNE
  return (u16)(u >> 16);
}
__device__ __forceinline__ float bf2f(u16 h) { return __uint_as_float(((u32)h) << 16); }
__device__ __forceinline__ u32 packsplit(float v) {
  u16 h = f2bf(v);
  u16 l = f2bf(v - bf2f(h));
  return (u32)h | ((u32)l << 16);
}

__device__ __forceinline__ float sigf(float x) { return 1.f / (1.f + __expf(-x)); }
__device__ __forceinline__ float tanh_f(float x) {
  float xx = fminf(20.f, fmaxf(-20.f, x));
  float e = __expf(-2.f * xx);
  return (1.f - e) / (1.f + e);
}

__device__ __forceinline__ floatx4 mfma3(short8 ah, short8 al, short8 bh, short8 bl, floatx4 acc) {
  acc = __builtin_amdgcn_mfma_f32_16x16x32_bf16(ah, bh, acc, 0, 0, 0);
  acc = __builtin_amdgcn_mfma_f32_16x16x32_bf16(ah, bl, acc, 0, 0, 0);
  acc = __builtin_amdgcn_mfma_f32_16x16x32_bf16(al, bh, acc, 0, 0, 0);
  return acc;
}

// write-through store: lands at the coherent point; no release fence needed.
__device__ __forceinline__ void st_sc_u32(u32* p, u32 v) {
  asm volatile("global_store_dword %0, %1, off sc0 sc1" :: "v"(p), "v"(v) : "memory");
}
#define WAITVM0() asm volatile("s_waitcnt vmcnt(0)" ::: "memory")

#define ALD(p) __hip_atomic_load((p), __ATOMIC_RELAXED, __HIP_MEMORY_SCOPE_AGENT)
#define AST(p, v) __hip_atomic_store((p), (v), __ATOMIC_RELAXED, __HIP_MEMORY_SCOPE_AGENT)

__device__ __forceinline__ int slotof(int u) { return u < 0 ? 0 : ((u & 63) + 1); }

// packed A-fragment load: 8 cols (2 slabs) for batch row m -> hi/lo short8 (cached loads)
__device__ __forceinline__ void ld_frag(const u32* p, short8& ah, short8& al) {
  uint4 a = *(const uint4*)p;
  uint4 b = *(const uint4*)(p + 256);
  union { u32 u[4]; short8 s; } H, L;
  H.u[0] = __builtin_amdgcn_perm(a.y, a.x, 0x05040100u);
  L.u[0] = __builtin_amdgcn_perm(a.y, a.x, 0x07060302u);
  H.u[1] = __builtin_amdgcn_perm(a.w, a.z, 0x05040100u);
  L.u[1] = __builtin_amdgcn_perm(a.w, a.z, 0x07060302u);
  H.u[2] = __builtin_amdgcn_perm(b.y, b.x, 0x05040100u);
  L.u[2] = __builtin_amdgcn_perm(b.y, b.x, 0x07060302u);
  H.u[3] = __builtin_amdgcn_perm(b.w, b.z, 0x05040100u);
  L.u[3] = __builtin_amdgcn_perm(b.w, b.z, 0x07060302u);
  ah = H.s; al = L.s;
}

// ---------------- prep kernels ----------------
__global__ void k_split_pair(const float* __restrict__ Wih, const float* __restrict__ Whh,
                             int ins, int K, u16* __restrict__ hi, u16* __restrict__ lo) {
  int n = NG * K;
  for (int idx = blockIdx.x * blockDim.x + threadIdx.x; idx < n; idx += gridDim.x * blockDim.x) {
    int row = idx / K;
    int k = idx - row * K;
    float v = (k < ins) ? Wih[row * ins + k] : Whh[row * HID + (k - ins)];
    u16 h = f2bf(v);
    hi[idx] = h;
    lo[idx] = f2bf(v - bf2f(h));
  }
}

__global__ void k_split_flat(const float* __restrict__ src, u16* __restrict__ hi,
                             u16* __restrict__ lo, int n) {
  for (int idx = blockIdx.x * blockDim.x + threadIdx.x; idx < n; idx += gridDim.x * blockDim.x) {
    float v = src[idx];
    u16 h = f2bf(v);
    hi[idx] = h;
    lo[idx] = f2bf(v - bf2f(h));
  }
}

// fused decoder-L0 weights: cols [0,512) = Wih0d @ fcW, cols [512,1024) = Whh0d
__global__ void k_fuse(const float* __restrict__ dWih0, const float* __restrict__ dWhh0,
                       const float* __restrict__ fcW,
                       u16* __restrict__ wfh, u16* __restrict__ wfl) {
  __shared__ float wr[FIN];
  const int row = blockIdx.x;            // gate row 0..2047
  if (threadIdx.x < FIN) wr[threadIdx.x] = dWih0[row * FIN + threadIdx.x];
  __syncthreads();
  for (int j = threadIdx.x; j < HID; j += blockDim.x) {
    float acc = 0.f;
#pragma unroll
    for (int f = 0; f < FIN; ++f) acc = fmaf(wr[f], fcW[f * HID + j], acc);
    u16 h = f2bf(acc);
    wfh[(size_t)row * K1 + j] = h;
    wfl[(size_t)row * K1 + j] = f2bf(acc - bf2f(h));
    float v2 = dWhh0[row * HID + j];
    u16 h2 = f2bf(v2);
    wfh[(size_t)row * K1 + HID + j] = h2;
    wfl[(size_t)row * K1 + HID + j] = f2bf(v2 - bf2f(h2));
  }
}

// gx[row][b] = Wih0d @ (x_last[b] - fcb);  beff[row] = bdih0+bdhh0+Wih0d@fcb
__global__ void k_gx(const float* __restrict__ dWih0, const float* __restrict__ in_seq,
                     const float* __restrict__ fcb, const float* __restrict__ bdih0,
                     const float* __restrict__ bdhh0, float* __restrict__ gx,
                     float* __restrict__ beff) {
  __shared__ float xl[BSZ * FIN];
  __shared__ float fb[FIN];
  const int row0 = blockIdx.x * 8;       // 256 blocks x 8 rows
  for (int i = threadIdx.x; i < BSZ * FIN; i += blockDim.x) {
    int b = i >> 6, f = i & 63;
    xl[i] = in_seq[(b * SEQT + (SEQT - 1)) * FIN + f];
  }
  if (threadIdx.x < FIN) fb[threadIdx.x] = fcb[threadIdx.x];
  __syncthreads();
  for (int i = threadIdx.x; i < 8 * BSZ; i += blockDim.x) {
    int r = row0 + (i >> 6);
    int b = i & 63;
    float acc = 0.f;
#pragma unroll 8
    for (int f = 0; f < FIN; ++f)
      acc = fmaf(dWih0[r * FIN + f], xl[(b << 6) + f] - fb[f], acc);
    gx[r * BSZ + b] = acc;
    if (b == 0) {
      float accb = 0.f;
#pragma unroll 8
      for (int f = 0; f < FIN; ++f) accb = fmaf(dWih0[r * FIN + f], fb[f], accb);
      beff[r] = bdih0[r] + bdhh0[r] + accb;
    }
  }
}

// input_seq [B][T][F] -> packed slabs xp[t][kb][m][j]
__global__ void k_pack_x(const float* __restrict__ x, u32* __restrict__ xp) {
  int n = BSZ * SEQT * FIN;
  for (int idx = blockIdx.x * blockDim.x + threadIdx.x; idx < n; idx += gridDim.x * blockDim.x) {
    int t = idx / (BSZ * FIN);
    int rem = idx - t * (BSZ * FIN);
    int b = rem >> 6;
    int f = rem & 63;
    u32 pk = packsplit(x[(b * SEQT + t) * FIN + f]);
    int off = ((f >> 2) * 64 + b) * 4 + (f & 3);
    xp[t * SLOT_XP + off] = pk;
  }
}

// ---------------- params ----------------
struct Params {
  const u16 *we0h, *we0l, *we1h, *we1l;
  const u16 *wd1h, *wd1l, *wfh, *wfl;
  const u16 *fch, *fcl;
  const u32 *xp;
  u32 *h0p, *h1p;
  const float *beih0, *behh0, *beih1, *behh1;
  const float *bdih1, *bdhh1;
  const float *gx, *beff;
  const float *fcb;
  float *out;
  u32 *cnt;
};

// ---------------- sync ----------------
// Master sweep: wave0 checks 128 own cells (2/lane) + optional 128 foreign + 4 fc cells.
__device__ void master_wait(u32* own, u32 ownT, u32* fore, u32 foreT, u32* fcf, u32 fcT) {
  if (threadIdx.x < 64) {
    int l = threadIdx.x;
    for (;;) {
      bool ok = ALD(own + l * 16) >= ownT && ALD(own + (l + 64) * 16) >= ownT;
      if (fore) ok = ok && ALD(fore + l * 16) >= foreT && ALD(fore + (l + 64) * 16) >= foreT;
      if (fcf && l < 4) ok = ok && ALD(fcf + l * 16) >= fcT;
      if (__all(ok)) break;
      __builtin_amdgcn_s_sleep(1);
    }
  }
  __syncthreads();
}

// sweep of a 128-cell done array
__device__ void sweep128(u32* arr, u32 T) {
  if (threadIdx.x < 64) {
    int l = threadIdx.x;
    while (!__all(ALD(arr + l * 16) >= T && ALD(arr + (l + 64) * 16) >= T))
      __builtin_amdgcn_s_sleep(1);
  }
  __syncthreads();
}

// Worker: poll OWN go cell only (1 poller per line). Keep the barrier — the two
// barrier-free variants (r2, r6) were the only two harness failures.
__device__ __forceinline__ void worker_wait(u32* cell, u32 tok) {
  if (threadIdx.x == 0) {
    while (ALD(cell) < tok) __builtin_amdgcn_s_sleep(1);
  }
  __syncthreads();
}

__device__ __forceinline__ void fence_acq() {
  __builtin_amdgcn_fence(__ATOMIC_ACQUIRE, "agent");   // epoch boundary only
}

// Arrival: drain own sc stores (each wave), then one token store to this block's cell.
__device__ __forceinline__ void arrive(u32* cell, u32 tok) {
  WAITVM0();
  __syncthreads();
  if (threadIdx.x == 0) AST(cell, tok);
}

// ---------------- W -> LDS (persistent) ----------------
template <bool IS_L1>
__device__ void load_w_lds(const u16* __restrict__ gh, const u16* __restrict__ gl,
                           u16* wh, u16* wl, int hc) {
  constexpr int K = IS_L1 ? K1 : K0;
  for (int i = threadIdx.x; i < 16 * K; i += NTHR) {
    int rr, k;
    if (IS_L1) { rr = i >> 10; k = i & 1023; }
    else       { rr = i / K0;  k = i - rr * K0; }
    int gc = ((rr >> 2) * HID) + hc + (rr & 3);   // row r -> gate q=r>>2, col j=r&3
    int dst = IS_L1 ? ((rr << 10) + ((((k >> 3) ^ rr)) << 3) + (k & 7))
                    : (rr * K0P + k);
    wh[dst] = gh[(size_t)gc * K + k];
    wl[dst] = gl[(size_t)gc * K + k];
  }
  __syncthreads();
}

// ---------------- K-range partial GEMM: acc += W[:, KBASE:KBASE+LEN] @ slab --------------
// Inline-asm load phase: 2*NIT global_load_dwordx4 issued back-to-back with "=v" register
// outputs (the allocator MUST keep them live -> all loads in flight at once), then ONE
// s_waitcnt vmcnt(0) + sched_barrier(0) (rule: hipcc hoists consumers above asm waitcnt
// without it). At 1 wave/SIMD there is no TLP; this is the only way to hide MALL latency.
// Accumulation order identical to before (bit-identical results).
template <bool IS_L1, int KBASE, int LEN>
__device__ __forceinline__ void kpart(const u32* __restrict__ sp,
                                      const u16* __restrict__ wh, const u16* __restrict__ wl,
                                      int r, int quad, int mo, floatx4& acc) {
  const int qo = quad << 3;
  constexpr int NIT = LEN / 32;
  uint4 ra[NIT], rb[NIT];
#pragma unroll
  for (int i = 0; i < NIT; ++i) {
    const u32* p = sp + (((i * 32 + qo) >> 2) << 8) + mo;
    asm volatile("global_load_dwordx4 %0, %1, off" : "=v"(ra[i]) : "v"(p));
    asm volatile("global_load_dwordx4 %0, %1, off offset:1024" : "=v"(rb[i]) : "v"(p));
  }
  asm volatile("s_waitcnt vmcnt(0)");
  __builtin_amdgcn_sched_barrier(0);
#pragma unroll
  for (int i = 0; i < NIT; ++i) {
    union { u32 u[4]; short8 s; } H, L;
    H.u[0] = __builtin_amdgcn_perm(ra[i].y, ra[i].x, 0x05040100u);
    L.u[0] = __builtin_amdgcn_perm(ra[i].y, ra[i].x, 0x07060302u);
    H.u[1] = __builtin_amdgcn_perm(ra[i].w, ra[i].z, 0x05040100u);
    L.u[1] = __builtin_amdgcn_perm(ra[i].w, ra[i].z, 0x07060302u);
    H.u[2] = __builtin_amdgcn_perm(rb[i].y, rb[i].x, 0x05040100u);
    L.u[2] = __builtin_amdgcn_perm(rb[i].y, rb[i].x, 0x07060302u);
    H.u[3] = __builtin_amdgcn_perm(rb[i].w, rb[i].z, 0x05040100u);
    L.u[3] = __builtin_amdgcn_perm(rb[i].w, rb[i].z, 0x07060302u);
    const int kg = i * 32 + KBASE;
    int woff;
    if (IS_L1) { int c = (kg >> 3) + quad; woff = (r << 10) + ((c ^ r) << 3); }
    else       { woff = r * K0P + kg + qo; }
    short8 bh = *(const short8*)(wh + woff);
    short8 bl = *(const short8*)(wl + woff);
    acc = mfma3(H.s, L.s, bh, bl, acc);
  }
}

// ---------------- epilogue: gates -> (h,c), packed write-through store ----------------
__device__ __forceinline__ void epilogue(floatx4 acc, floatx4 bs, float& creg,
                                         u32* __restrict__ oslab,
                                         const float* __restrict__ gxb) {
  const int tid = threadIdx.x, lane = tid & 63;
  const int j = lane & 3;
  const int isel = (lane >> 2) & 3;
  const int slb = lane & 48;
  float gate[4];
#pragma unroll
  for (int q = 0; q < 4; ++q) {
    const int sl = slb + (q << 2) + j;
    float t0 = __shfl(acc[0], sl, 64);
    float t1 = __shfl(acc[1], sl, 64);
    float t2 = __shfl(acc[2], sl, 64);
    float t3 = __shfl(acc[3], sl, 64);
    gate[q] = (isel == 0) ? t0 : (isel == 1) ? t1 : (isel == 2) ? t2 : t3;
  }
  if (gxb != nullptr) {
    const int bb = tid >> 2;
#pragma unroll
    for (int q = 0; q < 4; ++q) gate[q] += gxb[q * (HID * BSZ) + j * BSZ + bb];
  }
  float iv = gate[0] + bs[0];
  float fv = gate[1] + bs[1];
  float gv = gate[2] + bs[2];
  float ov = gate[3] + bs[3];
  float cn = fmaf(sigf(fv), creg, sigf(iv) * tanh_f(gv));
  float hn = sigf(ov) * tanh_f(cn);
  creg = cn;
  st_sc_u32(oslab + tid, packsplit(hn));   // wave-contiguous 256B write-through
}

// ---------------- decoder fc (dedicated blocks): out = dh1 @ fcW^T + fcb ----------------
__device__ void fc_step(int t, int blkq, const u32* __restrict__ h1slot,
                        const u16* __restrict__ fh, const u16* __restrict__ fl,
                        const float* __restrict__ fcb, float* __restrict__ out) {
  const int tid = threadIdx.x, lane = tid & 63, w = tid >> 6;
  const int quad = lane >> 4, r = lane & 15;
  const int m = (w << 4) + r;
  const int qo = quad << 3;
  const int mo = m << 2;
  const int col = (blkq << 4) + r;
  floatx4 acc = {0.f, 0.f, 0.f, 0.f};
#pragma unroll
  for (int kk = 0; kk < HID; kk += 32) {
    short8 ah, al;
    ld_frag(h1slot + (((kk + qo) >> 2) << 8) + mo, ah, al);
    short8 b1 = *(const short8*)(fh + col * HID + kk + qo);
    short8 b2 = *(const short8*)(fl + col * HID + kk + qo);
    acc = mfma3(ah, al, b1, b2, acc);
  }
  float bias = fcb[col];
#pragma unroll
  for (int i = 0; i < 4; ++i) {
    int b = (w << 4) + (quad << 2) + i;
    out[(b * FUTL + t) * FIN + col] = acc[i] + bias;
  }
}

// ---------------- the persistent kernel ----------------
__global__ __launch_bounds__(NTHR, 1) void lstm_coop(Params p) {
  __shared__ u16 wsmem[32768];              // 64 KB: hi at [0], lo at [16K]
  u16* wh = wsmem;
  u16* wl = wsmem + 16 * 1024;
  const int blk = blockIdx.x;
  const int tid = threadIdx.x;

  u32* fcf = FCF(p.cnt);
  u32* d0 = DONE0(p.cnt);
  u32* d1 = DONE1(p.cnt);

  if (blk >= NGRP) {
    // ======== dedicated fc blocks: consume h1-dec(t), produce out (off critical path) ====
    const int fi = blk - NGRP;              // 0..3, 16 out-cols each
    for (int t = 0; t < FUTL; ++t) {
      sweep128(d1, (u32)(513 + t));         // h1-dec(t) ready
      if ((t & 63) == 0) fence_acq();       // epoch boundary: recycled h1p lines
      fc_step(t, fi, p.h1p + (size_t)slotof(512 + t) * SLOT_HP,
              p.fch, p.fcl, p.fcb, p.out);
      WAITVM0();
      __syncthreads();
      if (tid == 0) AST(fcf + fi * 16, (u32)(t + 1));  // slot-protection token only
    }
    return;
  }

  const int grp = blk >> 7;
  const int lidx = blk & 127;
  const int hc = lidx << 2;
  const int lane = tid & 63, w = tid >> 6;
  const int quad = lane >> 4, r = lane & 15;
  const int mo = ((w << 4) + r) << 2;

  u32* goA = grp ? GOA1(p.cnt) : GOA0(p.cnt);
  u32* goB = grp ? GOB1(p.cnt) : GOB0(p.cnt);
  u32* myGoA = goA + lidx * 16;
  u32* myGoB = goB + lidx * 16;
  u32* myDone = (grp ? d1 : d0) + lidx * 16;

  floatx4 bse, bsd;
  {
    int ch = hc + (tid & 3);
    const float* bi  = grp ? p.beih1 : p.beih0;
    const float* bh2 = grp ? p.behh1 : p.behh0;
#pragma unroll
    for (int q = 0; q < 4; ++q) {
      bse[q] = bi[q * HID + ch] + bh2[q * HID + ch];
      bsd[q] = grp ? (p.bdih1[q * HID + ch] + p.bdhh1[q * HID + ch])
                   : p.beff[q * HID + ch];   // dec-L0 bias has Wih0d@fcb folded in
    }
  }
  float creg = 0.f;

  if (!grp) {
    // ======== group0: layer 0 ========
    load_w_lds<false>(p.we0h, p.we0l, wh, wl, hc);
    for (int s = 0; s < SEQT; ++s) {
      u32 tok = (u32)(s + 1);
      floatx4 acc = {0.f, 0.f, 0.f, 0.f};
      if (lidx == 0) {
        // own recurrence gate + far-lag slot gate on group1 (rarely binds)
        master_wait(d0, (u32)s, (s >= 63) ? d1 : nullptr, (u32)(s - 63), nullptr, 0u);
        if (tid < 127) AST(goA + ((tid + 1) << 4), tok);
        if ((s & 63) == 0 && s) fence_acq();
        kpart<false, 0, FIN>(p.xp + (size_t)s * SLOT_XP, wh, wl, r, quad, mo, acc);
      } else {
        // x-part has no cross-step dependency: compute it while waiting
        kpart<false, 0, FIN>(p.xp + (size_t)s * SLOT_XP, wh, wl, r, quad, mo, acc);
        worker_wait(myGoA, tok);
        if ((s & 63) == 0 && s) fence_acq();
      }
      kpart<false, FIN, HID>(p.h0p + (size_t)slotof(s - 1) * SLOT_HP, wh, wl, r, quad, mo, acc);
      epilogue(acc, bse, creg,
               p.h0p + (size_t)slotof(s) * SLOT_HP + (lidx << 8), nullptr);
      arrive(myDone, tok);
    }
    // decoder: fused weights [Weff | Whh0d], K=1024, layer-1-shaped step.
    load_w_lds<true>(p.wfh, p.wfl, wh, wl, hc);
    for (int t = 0; t < FUTL; ++t) {
      u32 tok = (u32)(513 + t);
      floatx4 acc = {0.f, 0.f, 0.f, 0.f};
      if (lidx == 0) {
        // own h0(511+t); t=0 also gates slot-1 overwrite (group1 past step 448)
        master_wait(d0, (u32)(512 + t), (t == 0) ? d1 : nullptr, 449u, nullptr, 0u);
        if (tid < 127) AST(goA + ((tid + 1) << 4), tok);
      } else {
        worker_wait(myGoA, tok);
      }
      if ((t & 63) == 0) fence_acq();        // u=512, 576 epoch boundaries
      kpart<true, 512, HID>(p.h0p + (size_t)slotof(511 + t) * SLOT_HP, wh, wl, r, quad, mo, acc);
      if (t) {
        // cross gate: h1(511+t) feeds the fused Weff part
        if (lidx == 0) {
          sweep128(d1, (u32)(512 + t));
          if (tid < 127) AST(goB + ((tid + 1) << 4), tok);
        } else {
          worker_wait(myGoB, tok);
        }
        kpart<true, 0, HID>(p.h1p + (size_t)slotof(511 + t) * SLOT_HP, wh, wl, r, quad, mo, acc);
      }
      epilogue(acc, bsd, creg,
               p.h0p + (size_t)slotof(512 + t) * SLOT_HP + (lidx << 8),
               (t == 0) ? (p.gx + hc * BSZ) : nullptr);
      arrive(myDone, tok);
    }
  } else {
    // ======== group1: layer 1 ========
    load_w_lds<true>(p.we1h, p.we1l, wh, wl, hc);
    for (int t = 0; t < SEQT; ++t) {
      u32 tok = (u32)(t + 1);
      floatx4 acc = {0.f, 0.f, 0.f, 0.f};
      if (lidx == 0) {
        master_wait(d1, (u32)t, nullptr, 0u, nullptr, 0u);   // own h1(t-1)
        if (tid < 127) AST(goA + ((tid + 1) << 4), tok);
      } else {
        worker_wait(myGoA, tok);
      }
      if ((t & 63) == 0 && t) fence_acq();
      kpart<true, 512, HID>(p.h1p + (size_t)slotof(t - 1) * SLOT_HP, wh, wl, r, quad, mo, acc);
      if (lidx == 0) {
        sweep128(d0, (u32)(t + 1));                          // cross: h0(t)
        if (tid < 127) AST(goB + ((tid + 1) << 4), tok);
      } else {
        worker_wait(myGoB, tok);
      }
      kpart<true, 0, HID>(p.h0p + (size_t)slotof(t) * SLOT_HP, wh, wl, r, quad, mo, acc);
      epilogue(acc, bse, creg,
               p.h1p + (size_t)slotof(t) * SLOT_HP + (lidx << 8), nullptr);
      arrive(myDone, tok);
    }
    load_w_lds<true>(p.wd1h, p.wd1l, wh, wl, hc);
    for (int t = 0; t < FUTL; ++t) {
      u32 tok = (u32)(513 + t);
      floatx4 acc = {0.f, 0.f, 0.f, 0.f};
      if (lidx == 0) {
        // own h1(511+t); fcf far-lag protects h1p slot reuse for fc readers
        master_wait(d1, (u32)(512 + t), nullptr, 0u,
                    (t >= 64) ? fcf : nullptr, (u32)(t - 63));
        if (tid < 127) AST(goA + ((tid + 1) << 4), tok);
      } else {
        worker_wait(myGoA, tok);
      }
      if ((t & 63) == 0) fence_acq();
      kpart<true, 512, HID>(p.h1p + (size_t)slotof(511 + t) * SLOT_HP, wh, wl, r, quad, mo, acc);
      if (lidx == 0) {
        sweep128(d0, (u32)(513 + t));                        // cross: h0-dec(t)
        if (tid < 127) AST(goB + ((tid + 1) << 4), tok);
      } else {
        worker_wait(myGoB, tok);
      }
      kpart<true, 0, HID>(p.h0p + (size_t)slotof(512 + t) * SLOT_HP, wh, wl, r, quad, mo, acc);
      epilogue(acc, bsd, creg,
               p.h1p + (size_t)slotof(512 + t) * SLOT_HP + (lidx << 8), nullptr);
      arrive(myDone, tok);
    }
  }
}

// ---------------- launch ----------------
extern "C" void kernel_launch(void* const* d_in, const int* in_sizes, int n_in,
                              void* d_out, int out_size, void* d_ws, size_t ws_size,
                              hipStream_t stream) {
  (void)in_sizes; (void)n_in; (void)out_size; (void)ws_size;
  const float* in_seq = (const float*)d_in[0];
  const float* eWih0 = (const float*)d_in[1];
  const float* eWhh0 = (const float*)d_in[2];
  const float* ebih0 = (const float*)d_in[3];
  const float* ebhh0 = (const float*)d_in[4];
  const float* eWih1 = (const float*)d_in[5];
  const float* eWhh1 = (const float*)d_in[6];
  const float* ebih1 = (const float*)d_in[7];
  const float* ebhh1 = (const float*)d_in[8];
  const float* dWih0 = (const float*)d_in[9];
  const float* dWhh0 = (const float*)d_in[10];
  const float* dbih0 = (const float*)d_in[11];
  const float* dbhh0 = (const float*)d_in[12];
  const float* dWih1 = (const float*)d_in[13];
  const float* dWhh1 = (const float*)d_in[14];
  const float* dbih1 = (const float*)d_in[15];
  const float* dbhh1 = (const float*)d_in[16];
  const float* fcW  = (const float*)d_in[17];
  const float* fcb  = (const float*)d_in[18];

  char* ws = (char*)d_ws;
  u16* we0h = (u16*)(ws + OFF_WHI_E0); u16* we0l = (u16*)(ws + OFF_WLO_E0);
  u16* we1h = (u16*)(ws + OFF_WHI_E1); u16* we1l = (u16*)(ws + OFF_WLO_E1);
  u16* wd1h = (u16*)(ws + OFF_WHI_D1); u16* wd1l = (u16*)(ws + OFF_WLO_D1);
  u16* wfh  = (u16*)(ws + OFF_WFH);    u16* wfl  = (u16*)(ws + OFF_WFL);
  u16* fch  = (u16*)(ws + OFF_FCHI);   u16* fcl  = (u16*)(ws + OFF_FCLO);
  float* gx   = (float*)(ws + OFF_GX);
  float* beff = (float*)(ws + OFF_BEFF);
  u32* xp   = (u32*)(ws + OFF_XP);
  u32* h0p  = (u32*)(ws + OFF_H0P);
  u32* h1p  = (u32*)(ws + OFF_H1P);
  u32* cnt  = (u32*)(ws + OFF_CNT);

  // zero: h0/h1 slot 0 (initial state) + counter region (ws poisoned 0xAA each call)
  hipMemsetAsync(ws + OFF_H0P, 0, (size_t)SLOT_HP * 4, stream);
  hipMemsetAsync(ws + OFF_H1P, 0, (size_t)SLOT_HP * 4, stream);
  hipMemsetAsync(ws + OFF_CNT, 0, CNT_BYTES, stream);

  k_split_pair<<<512, 256, 0, stream>>>(eWih0, eWhh0, FIN, K0, we0h, we0l);
  k_split_pair<<<512, 256, 0, stream>>>(eWih1, eWhh1, HID, K1, we1h, we1l);
  k_split_pair<<<512, 256, 0, stream>>>(dWih1, dWhh1, HID, K1, wd1h, wd1l);
  k_split_flat<<<128, 256, 0, stream>>>(fcW, fch, fcl, FIN * HID);
  k_fuse<<<NG, 256, 0, stream>>>(dWih0, dWhh0, fcW, wfh, wfl);
  k_gx<<<256, 256, 0, stream>>>(dWih0, in_seq, fcb, dbih0, dbhh0, gx, beff);
  k_pack_x<<<1024, 256, 0, stream>>>(in_seq, xp);

  Params p;
  p.we0h = we0h; p.we0l = we0l; p.we1h = we1h; p.we1l = we1l;
  p.wd1h = wd1h; p.wd1l = wd1l; p.wfh = wfh; p.wfl = wfl;
  p.fch = fch; p.fcl = fcl;
  p.xp = xp; p.h0p = h0p; p.h1p = h1p;
  p.beih0 = ebih0; p.behh0 = ebhh0; p.beih1 = ebih1; p.behh1 = ebhh1;
  p.bdih1 = dbih1; p.bdhh1 = dbhh1;
  p.gx = gx; p.beff = beff;
  p.fcb = fcb;
  p.out = (float*)d_out;
  p.cnt = cnt;

  lstm_coop<<<dim3(NBLK), dim3(NTHR), 0, stream>>>(p);
}

// Round 9
// 4272.145 us; speedup vs baseline: 1.1898x; 1.1898x over previous
//
#include <hip/hip_runtime.h>
#include <stdint.h>

typedef __attribute__((ext_vector_type(8))) short short8;
typedef __attribute__((ext_vector_type(4))) float floatx4;
typedef unsigned short u16;
typedef unsigned int u32;

constexpr int BSZ = 64;     // batch
constexpr int SEQT = 512;   // encoder timesteps
constexpr int FIN = 64;     // input features F
constexpr int HID = 512;    // hidden H
constexpr int NG = 2048;    // 4*H gate rows
constexpr int FUTL = 96;    // decoder steps
constexpr int K0 = FIN + HID;   // 576
constexpr int K1 = HID + HID;   // 1024
constexpr int K0P = K0 + 8;     // padded LDS row stride for layer-0 W
constexpr int NGRP = 256;       // layer-group blocks (2 groups x 128)
constexpr int NFCB = 4;         // dedicated fc blocks (off critical path)
constexpr int NBLK = NGRP + NFCB;
constexpr int NTHR = 256;

// packed activation slabs: one slab = 4 cols x 64 batch x u32(hi|lo<<16) = 1KB
constexpr int SLOT_HP = 128 * 256;  // u32 per h slot (128 slabs)
constexpr int SLOT_XP = 16 * 256;   // u32 per x slot (16 slabs)
constexpr int NSLOT_H = 65;         // slot 0 = zeros; slot(u) = u%64+1

// ---------------- workspace layout (bytes) ----------------
constexpr size_t S_W0 = (size_t)NG * K0 * 2;
constexpr size_t S_W1 = (size_t)NG * K1 * 2;
constexpr size_t S_FC = (size_t)FIN * HID * 2;

constexpr size_t OFF_WHI_E0 = 0;
constexpr size_t OFF_WLO_E0 = OFF_WHI_E0 + S_W0;
constexpr size_t OFF_WHI_E1 = OFF_WLO_E0 + S_W0;
constexpr size_t OFF_WLO_E1 = OFF_WHI_E1 + S_W1;
constexpr size_t OFF_WHI_D1 = OFF_WLO_E1 + S_W1;
constexpr size_t OFF_WLO_D1 = OFF_WHI_D1 + S_W1;
constexpr size_t OFF_WFH   = OFF_WLO_D1 + S_W1;  // fused dec-L0 [2048][1024] = [Wih0d@fcW | Whh0d]
constexpr size_t OFF_WFL   = OFF_WFH + S_W1;
constexpr size_t OFF_FCHI  = OFF_WFL + S_W1;
constexpr size_t OFF_FCLO  = OFF_FCHI + S_FC;
constexpr size_t OFF_GX    = OFF_FCLO + S_FC;               // [2048][64] f32: Wih0d@(x_last - fcb)
constexpr size_t OFF_BEFF  = OFF_GX + (size_t)NG * BSZ * 4; // [2048] f32: bdih0+bdhh0+Wih0d@fcb
constexpr size_t OFF_XP    = OFF_BEFF + (size_t)NG * 4;     // 512 slots
constexpr size_t OFF_H0P   = OFF_XP + (size_t)SEQT * SLOT_XP * 4;
constexpr size_t OFF_H1P   = OFF_H0P + (size_t)NSLOT_H * SLOT_HP * 4;
constexpr size_t OFF_CNT   = OFF_H1P + (size_t)NSLOT_H * SLOT_HP * 4;
constexpr size_t CNT_BYTES = 65536;

// cnt layout (u32 idx): fcdone @0 (4 cells x16); done0 @256 (128x16); done1 @2304;
// goA0 @4352; goB0 @6400; goA1 @8448; goB1 @10496.
// goA*: own-master "stage go" broadcast. goB*: FOREIGN master's progress broadcast
// (goB0[i] = g1's proven d1 progress, written by g1-master; goB1[i] = g0's d0 progress).
#define FCF(c)   ((c) + 0)
#define DONE0(c) ((c) + 256)
#define DONE1(c) ((c) + 2304)
#define GOA0(c)  ((c) + 4352)
#define GOB0(c)  ((c) + 6400)
#define GOA1(c)  ((c) + 8448)
#define GOB1(c)  ((c) + 10496)

// ---------------- bf16 helpers ----------------
__device__ __forceinline__ u16 f2bf(float f) {
  u32 u = __float_as_uint(f);
  u += 0x7FFFu + ((u >> 16) & 1u);   // RNE
  return (u16)(u >> 16);
}
__device__ __forceinline__ float bf2f(u16 h) { return __uint_as_float(((u32)h) << 16); }
__device__ __forceinline__ u32 packsplit(float v) {
  u16 h = f2bf(v);
  u16 l = f2bf(v - bf2f(h));
  return (u32)h | ((u32)l << 16);
}

__device__ __forceinline__ float sigf(float x) { return 1.f / (1.f + __expf(-x)); }
__device__ __forceinline__ float tanh_f(float x) {
  float xx = fminf(20.f, fmaxf(-20.f, x));
  float e = __expf(-2.f * xx);
  return (1.f - e) / (1.f + e);
}

__device__ __forceinline__ floatx4 mfma3(short8 ah, short8 al, short8 bh, short8 bl, floatx4 acc) {
  acc = __builtin_amdgcn_mfma_f32_16x16x32_bf16(ah, bh, acc, 0, 0, 0);
  acc = __builtin_amdgcn_mfma_f32_16x16x32_bf16(ah, bl, acc, 0, 0, 0);
  acc = __builtin_amdgcn_mfma_f32_16x16x32_bf16(al, bh, acc, 0, 0, 0);
  return acc;
}

// write-through store: lands at the coherent point; no release fence needed.
__device__ __forceinline__ void st_sc_u32(u32* p, u32 v) {
  asm volatile("global_store_dword %0, %1, off sc0 sc1" :: "v"(p), "v"(v) : "memory");
}
#define WAITVM0() asm volatile("s_waitcnt vmcnt(0)" ::: "memory")

#define ALD(p) __hip_atomic_load((p), __ATOMIC_RELAXED, __HIP_MEMORY_SCOPE_AGENT)
#define AST(p, v) __hip_atomic_store((p), (v), __ATOMIC_RELAXED, __HIP_MEMORY_SCOPE_AGENT)

__device__ __forceinline__ int slotof(int u) { return u < 0 ? 0 : ((u & 63) + 1); }

// packed A-fragment load: 8 cols (2 slabs) for batch row m -> hi/lo short8 (cached loads)
__device__ __forceinline__ void ld_frag(const u32* p, short8& ah, short8& al) {
  uint4 a = *(const uint4*)p;
  uint4 b = *(const uint4*)(p + 256);
  union { u32 u[4]; short8 s; } H, L;
  H.u[0] = __builtin_amdgcn_perm(a.y, a.x, 0x05040100u);
  L.u[0] = __builtin_amdgcn_perm(a.y, a.x, 0x07060302u);
  H.u[1] = __builtin_amdgcn_perm(a.w, a.z, 0x05040100u);
  L.u[1] = __builtin_amdgcn_perm(a.w, a.z, 0x07060302u);
  H.u[2] = __builtin_amdgcn_perm(b.y, b.x, 0x05040100u);
  L.u[2] = __builtin_amdgcn_perm(b.y, b.x, 0x07060302u);
  H.u[3] = __builtin_amdgcn_perm(b.w, b.z, 0x05040100u);
  L.u[3] = __builtin_amdgcn_perm(b.w, b.z, 0x07060302u);
  ah = H.s; al = L.s;
}

// ---------------- prep kernels ----------------
__global__ void k_split_pair(const float* __restrict__ Wih, const float* __restrict__ Whh,
                             int ins, int K, u16* __restrict__ hi, u16* __restrict__ lo) {
  int n = NG * K;
  for (int idx = blockIdx.x * blockDim.x + threadIdx.x; idx < n; idx += gridDim.x * blockDim.x) {
    int row = idx / K;
    int k = idx - row * K;
    float v = (k < ins) ? Wih[row * ins + k] : Whh[row * HID + (k - ins)];
    u16 h = f2bf(v);
    hi[idx] = h;
    lo[idx] = f2bf(v - bf2f(h));
  }
}

__global__ void k_split_flat(const float* __restrict__ src, u16* __restrict__ hi,
                             u16* __restrict__ lo, int n) {
  for (int idx = blockIdx.x * blockDim.x + threadIdx.x; idx < n; idx += gridDim.x * blockDim.x) {
    float v = src[idx];
    u16 h = f2bf(v);
    hi[idx] = h;
    lo[idx] = f2bf(v - bf2f(h));
  }
}

// fused decoder-L0 weights: cols [0,512) = Wih0d @ fcW, cols [512,1024) = Whh0d
__global__ void k_fuse(const float* __restrict__ dWih0, const float* __restrict__ dWhh0,
                       const float* __restrict__ fcW,
                       u16* __restrict__ wfh, u16* __restrict__ wfl) {
  __shared__ float wr[FIN];
  const int row = blockIdx.x;            // gate row 0..2047
  if (threadIdx.x < FIN) wr[threadIdx.x] = dWih0[row * FIN + threadIdx.x];
  __syncthreads();
  for (int j = threadIdx.x; j < HID; j += blockDim.x) {
    float acc = 0.f;
#pragma unroll
    for (int f = 0; f < FIN; ++f) acc = fmaf(wr[f], fcW[f * HID + j], acc);
    u16 h = f2bf(acc);
    wfh[(size_t)row * K1 + j] = h;
    wfl[(size_t)row * K1 + j] = f2bf(acc - bf2f(h));
    float v2 = dWhh0[row * HID + j];
    u16 h2 = f2bf(v2);
    wfh[(size_t)row * K1 + HID + j] = h2;
    wfl[(size_t)row * K1 + HID + j] = f2bf(v2 - bf2f(h2));
  }
}

// gx[row][b] = Wih0d @ (x_last[b] - fcb);  beff[row] = bdih0+bdhh0+Wih0d@fcb
__global__ void k_gx(const float* __restrict__ dWih0, const float* __restrict__ in_seq,
                     const float* __restrict__ fcb, const float* __restrict__ bdih0,
                     const float* __restrict__ bdhh0, float* __restrict__ gx,
                     float* __restrict__ beff) {
  __shared__ float xl[BSZ * FIN];
  __shared__ float fb[FIN];
  const int row0 = blockIdx.x * 8;       // 256 blocks x 8 rows
  for (int i = threadIdx.x; i < BSZ * FIN; i += blockDim.x) {
    int b = i >> 6, f = i & 63;
    xl[i] = in_seq[(b * SEQT + (SEQT - 1)) * FIN + f];
  }
  if (threadIdx.x < FIN) fb[threadIdx.x] = fcb[threadIdx.x];
  __syncthreads();
  for (int i = threadIdx.x; i < 8 * BSZ; i += blockDim.x) {
    int r = row0 + (i >> 6);
    int b = i & 63;
    float acc = 0.f;
#pragma unroll 8
    for (int f = 0; f < FIN; ++f)
      acc = fmaf(dWih0[r * FIN + f], xl[(b << 6) + f] - fb[f], acc);
    gx[r * BSZ + b] = acc;
    if (b == 0) {
      float accb = 0.f;
#pragma unroll 8
      for (int f = 0; f < FIN; ++f) accb = fmaf(dWih0[r * FIN + f], fb[f], accb);
      beff[r] = bdih0[r] + bdhh0[r] + accb;
    }
  }
}

// input_seq [B][T][F] -> packed slabs xp[t][kb][m][j]
__global__ void k_pack_x(const float* __restrict__ x, u32* __restrict__ xp) {
  int n = BSZ * SEQT * FIN;
  for (int idx = blockIdx.x * blockDim.x + threadIdx.x; idx < n; idx += gridDim.x * blockDim.x) {
    int t = idx / (BSZ * FIN);
    int rem = idx - t * (BSZ * FIN);
    int b = rem >> 6;
    int f = rem & 63;
    u32 pk = packsplit(x[(b * SEQT + t) * FIN + f]);
    int off = ((f >> 2) * 64 + b) * 4 + (f & 3);
    xp[t * SLOT_XP + off] = pk;
  }
}

// ---------------- params ----------------
struct Params {
  const u16 *we0h, *we0l, *we1h, *we1l;
  const u16 *wd1h, *wd1l, *wfh, *wfl;
  const u16 *fch, *fcl;
  const u32 *xp;
  u32 *h0p, *h1p;
  const float *beih0, *behh0, *beih1, *behh1;
  const float *bdih1, *bdhh1;
  const float *gx, *beff;
  const float *fcb;
  float *out;
  u32 *cnt;
};

// ---------------- sync ----------------
// Master sweep: wave0 checks 128 own cells (2/lane) + optional 4 fc cells.
__device__ void master_wait(u32* own, u32 ownT, u32* fcf, u32 fcT) {
  if (threadIdx.x < 64) {
    int l = threadIdx.x;
    for (;;) {
      bool ok = ALD(own + l * 16) >= ownT && ALD(own + (l + 64) * 16) >= ownT;
      if (fcf && l < 4) ok = ok && ALD(fcf + l * 16) >= fcT;
      if (__all(ok)) break;
      __builtin_amdgcn_s_sleep(1);
    }
  }
  __syncthreads();
}

// sweep of a 128-cell done array
__device__ void sweep128(u32* arr, u32 T) {
  if (threadIdx.x < 64) {
    int l = threadIdx.x;
    while (!__all(ALD(arr + l * 16) >= T && ALD(arr + (l + 64) * 16) >= T))
      __builtin_amdgcn_s_sleep(1);
  }
  __syncthreads();
}

// Single-cell wait: 1 poller per line (proven shape; barrier-free variants hung).
__device__ __forceinline__ void worker_wait(u32* cell, u32 tok) {
  if (threadIdx.x == 0) {
    while (ALD(cell) < tok) __builtin_amdgcn_s_sleep(1);
  }
  __syncthreads();
}

__device__ __forceinline__ void fence_acq() {
  __builtin_amdgcn_fence(__ATOMIC_ACQUIRE, "agent");   // epoch boundary only
}

// Arrival: drain own sc stores (each wave), then one token store to this block's cell.
__device__ __forceinline__ void arrive(u32* cell, u32 tok) {
  WAITVM0();
  __syncthreads();
  if (threadIdx.x == 0) AST(cell, tok);
}

// Master dual broadcast: tids 1..127 -> own group's goA cells (stage token);
// tids 128..255 -> FOREIGN group's goB cells (own-done progress value).
__device__ __forceinline__ void bcast(u32* goA, u32 tokA, u32* goBF, u32 prog) {
  const int tid = threadIdx.x;
  if (tid >= 1 && tid < 128) AST(goA + (tid << 4), tokA);
  else if (tid >= 128) AST(goBF + ((tid - 128) << 4), prog);
}

// ---------------- W -> LDS (persistent) ----------------
template <bool IS_L1>
__device__ void load_w_lds(const u16* __restrict__ gh, const u16* __restrict__ gl,
                           u16* wh, u16* wl, int hc) {
  constexpr int K = IS_L1 ? K1 : K0;
  for (int i = threadIdx.x; i < 16 * K; i += NTHR) {
    int rr, k;
    if (IS_L1) { rr = i >> 10; k = i & 1023; }
    else       { rr = i / K0;  k = i - rr * K0; }
    int gc = ((rr >> 2) * HID) + hc + (rr & 3);   // row r -> gate q=r>>2, col j=r&3
    int dst = IS_L1 ? ((rr << 10) + ((((k >> 3) ^ rr)) << 3) + (k & 7))
                    : (rr * K0P + k);
    wh[dst] = gh[(size_t)gc * K + k];
    wl[dst] = gl[(size_t)gc * K + k];
  }
  __syncthreads();
}

// ---------------- K-range partial GEMM: acc += W[:, KBASE:KBASE+LEN] @ slab --------------
// r5 form (measured best): two-phase source shape, compiler free to pipeline loads
// under MFMAs. Accumulation order identical across rounds (bit-identical results).
template <bool IS_L1, int KBASE, int LEN>
__device__ __forceinline__ void kpart(const u32* __restrict__ sp,
                                      const u16* __restrict__ wh, const u16* __restrict__ wl,
                                      int r, int quad, int mo, floatx4& acc) {
  const int qo = quad << 3;
  constexpr int NIT = LEN / 32;
  uint4 ra[NIT], rb[NIT];
#pragma unroll
  for (int i = 0; i < NIT; ++i) {
    const u32* p = sp + (((i * 32 + qo) >> 2) << 8) + mo;
    ra[i] = *(const uint4*)p;
    rb[i] = *(const uint4*)(p + 256);
  }
#pragma unroll
  for (int i = 0; i < NIT; ++i) {
    union { u32 u[4]; short8 s; } H, L;
    H.u[0] = __builtin_amdgcn_perm(ra[i].y, ra[i].x, 0x05040100u);
    L.u[0] = __builtin_amdgcn_perm(ra[i].y, ra[i].x, 0x07060302u);
    H.u[1] = __builtin_amdgcn_perm(ra[i].w, ra[i].z, 0x05040100u);
    L.u[1] = __builtin_amdgcn_perm(ra[i].w, ra[i].z, 0x07060302u);
    H.u[2] = __builtin_amdgcn_perm(rb[i].y, rb[i].x, 0x05040100u);
    L.u[2] = __builtin_amdgcn_perm(rb[i].y, rb[i].x, 0x07060302u);
    H.u[3] = __builtin_amdgcn_perm(rb[i].w, rb[i].z, 0x05040100u);
    L.u[3] = __builtin_amdgcn_perm(rb[i].w, rb[i].z, 0x07060302u);
    const int kg = i * 32 + KBASE;
    int woff;
    if (IS_L1) { int c = (kg >> 3) + quad; woff = (r << 10) + ((c ^ r) << 3); }
    else       { woff = r * K0P + kg + qo; }
    short8 bh = *(const short8*)(wh + woff);
    short8 bl = *(const short8*)(wl + woff);
    acc = mfma3(H.s, L.s, bh, bl, acc);
  }
}

// ---------------- epilogue: gates -> (h,c), packed write-through store ----------------
__device__ __forceinline__ void epilogue(floatx4 acc, floatx4 bs, float& creg,
                                         u32* __restrict__ oslab,
                                         const float* __restrict__ gxb) {
  const int tid = threadIdx.x, lane = tid & 63;
  const int j = lane & 3;
  const int isel = (lane >> 2) & 3;
  const int slb = lane & 48;
  float gate[4];
#pragma unroll
  for (int q = 0; q < 4; ++q) {
    const int sl = slb + (q << 2) + j;
    float t0 = __shfl(acc[0], sl, 64);
    float t1 = __shfl(acc[1], sl, 64);
    float t2 = __shfl(acc[2], sl, 64);
    float t3 = __shfl(acc[3], sl, 64);
    gate[q] = (isel == 0) ? t0 : (isel == 1) ? t1 : (isel == 2) ? t2 : t3;
  }
  if (gxb != nullptr) {
    const int bb = tid >> 2;
#pragma unroll
    for (int q = 0; q < 4; ++q) gate[q] += gxb[q * (HID * BSZ) + j * BSZ + bb];
  }
  float iv = gate[0] + bs[0];
  float fv = gate[1] + bs[1];
  float gv = gate[2] + bs[2];
  float ov = gate[3] + bs[3];
  float cn = fmaf(sigf(fv), creg, sigf(iv) * tanh_f(gv));
  float hn = sigf(ov) * tanh_f(cn);
  creg = cn;
  st_sc_u32(oslab + tid, packsplit(hn));   // wave-contiguous 256B write-through
}

// ---------------- decoder fc (dedicated blocks): out = dh1 @ fcW^T + fcb ----------------
__device__ void fc_step(int t, int blkq, const u32* __restrict__ h1slot,
                        const u16* __restrict__ fh, const u16* __restrict__ fl,
                        const float* __restrict__ fcb, float* __restrict__ out) {
  const int tid = threadIdx.x, lane = tid & 63, w = tid >> 6;
  const int quad = lane >> 4, r = lane & 15;
  const int m = (w << 4) + r;
  const int qo = quad << 3;
  const int mo = m << 2;
  const int col = (blkq << 4) + r;
  floatx4 acc = {0.f, 0.f, 0.f, 0.f};
#pragma unroll
  for (int kk = 0; kk < HID; kk += 32) {
    short8 ah, al;
    ld_frag(h1slot + (((kk + qo) >> 2) << 8) + mo, ah, al);
    short8 b1 = *(const short8*)(fh + col * HID + kk + qo);
    short8 b2 = *(const short8*)(fl + col * HID + kk + qo);
    acc = mfma3(ah, al, b1, b2, acc);
  }
  float bias = fcb[col];
#pragma unroll
  for (int i = 0; i < 4; ++i) {
    int b = (w << 4) + (quad << 2) + i;
    out[(b * FUTL + t) * FIN + col] = acc[i] + bias;
  }
}

// ---------------- the persistent kernel ----------------
__global__ __launch_bounds__(NTHR, 1) void lstm_coop(Params p) {
  __shared__ u16 wsmem[32768];              // 64 KB: hi at [0], lo at [16K]
  u16* wh = wsmem;
  u16* wl = wsmem + 16 * 1024;
  const int blk = blockIdx.x;
  const int tid = threadIdx.x;

  u32* fcf = FCF(p.cnt);
  u32* d0 = DONE0(p.cnt);
  u32* d1 = DONE1(p.cnt);

  if (blk >= NGRP) {
    // ======== dedicated fc blocks: consume h1-dec(t), produce out (off critical path) ====
    const int fi = blk - NGRP;              // 0..3, 16 out-cols each
    for (int t = 0; t < FUTL; ++t) {
      sweep128(d1, (u32)(513 + t));         // h1-dec(t) ready
      if ((t & 63) == 0) fence_acq();       // epoch boundary: recycled h1p lines
      fc_step(t, fi, p.h1p + (size_t)slotof(512 + t) * SLOT_HP,
              p.fch, p.fcl, p.fcb, p.out);
      WAITVM0();
      __syncthreads();
      if (tid == 0) AST(fcf + fi * 16, (u32)(t + 1));  // slot-protection token only
    }
    return;
  }

  const int grp = blk >> 7;
  const int lidx = blk & 127;
  const int hc = lidx << 2;
  const int lane = tid & 63, w = tid >> 6;
  const int quad = lane >> 4, r = lane & 15;
  const int mo = ((w << 4) + r) << 2;

  u32* goA  = grp ? GOA1(p.cnt) : GOA0(p.cnt);
  u32* goBF = grp ? GOB0(p.cnt) : GOB1(p.cnt);   // FOREIGN group's progress cells (master writes)
  u32* myGoA = goA + lidx * 16;
  u32* myGoB = (grp ? GOB1(p.cnt) : GOB0(p.cnt)) + lidx * 16;  // own cell, foreign master writes
  u32* myDone = (grp ? d1 : d0) + lidx * 16;

  floatx4 bse, bsd;
  {
    int ch = hc + (tid & 3);
    const float* bi  = grp ? p.beih1 : p.beih0;
    const float* bh2 = grp ? p.behh1 : p.behh0;
#pragma unroll
    for (int q = 0; q < 4; ++q) {
      bse[q] = bi[q * HID + ch] + bh2[q * HID + ch];
      bsd[q] = grp ? (p.bdih1[q * HID + ch] + p.bdhh1[q * HID + ch])
                   : p.beff[q * HID + ch];   // dec-L0 bias has Wih0d@fcb folded in
    }
  }
  float creg = 0.f;

  if (!grp) {
    // ======== group0: layer 0 ========
    load_w_lds<false>(p.we0h, p.we0l, wh, wl, hc);
    for (int s = 0; s < SEQT; ++s) {
      u32 tok = (u32)(s + 1);
      floatx4 acc = {0.f, 0.f, 0.f, 0.f};
      if (lidx == 0) {
        master_wait(d0, (u32)s, nullptr, 0u);            // own recurrence gate
        if (s >= 63) worker_wait(myGoB, (u32)(s - 63));  // far-lag slot gate (g1 progress)
        bcast(goA, tok, goBF, (u32)s);                   // goA + publish d0>=s to group1
        if ((s & 63) == 0 && s) fence_acq();
        kpart<false, 0, FIN>(p.xp + (size_t)s * SLOT_XP, wh, wl, r, quad, mo, acc);
      } else {
        // x-part has no cross-step dependency: compute it while waiting
        kpart<false, 0, FIN>(p.xp + (size_t)s * SLOT_XP, wh, wl, r, quad, mo, acc);
        worker_wait(myGoA, tok);
        if ((s & 63) == 0 && s) fence_acq();
      }
      kpart<false, FIN, HID>(p.h0p + (size_t)slotof(s - 1) * SLOT_HP, wh, wl, r, quad, mo, acc);
      epilogue(acc, bse, creg,
               p.h0p + (size_t)slotof(s) * SLOT_HP + (lidx << 8), nullptr);
      arrive(myDone, tok);
    }
    // transition: publish d0>=512 BEFORE the dec weight load (g1 enc s=511 needs it)
    if (lidx == 0) {
      sweep128(d0, 512u);
      if (tid >= 128) AST(goBF + ((tid - 128) << 4), 512u);
    }
    // decoder: fused weights [Weff | Whh0d], K=1024, layer-1-shaped step.
    load_w_lds<true>(p.wfh, p.wfl, wh, wl, hc);
    for (int t = 0; t < FUTL; ++t) {
      u32 tok = (u32)(513 + t);
      floatx4 acc = {0.f, 0.f, 0.f, 0.f};
      if (lidx == 0) {
        master_wait(d0, (u32)(512 + t), nullptr, 0u);    // own h0(511+t)
        if (t == 0) worker_wait(myGoB, 449u);            // slot-1 overwrite gate (d1>=449)
        bcast(goA, tok, goBF, (u32)(512 + t));
      } else {
        worker_wait(myGoA, tok);
      }
      if ((t & 63) == 0) fence_acq();        // u=512, 576 epoch boundaries
      kpart<true, 512, HID>(p.h0p + (size_t)slotof(511 + t) * SLOT_HP, wh, wl, r, quad, mo, acc);
      if (t) {
        // cross: h1(511+t) feeds the fused Weff part; g1-master published d1>=512+t
        worker_wait(myGoB, (u32)(512 + t));
        kpart<true, 0, HID>(p.h1p + (size_t)slotof(511 + t) * SLOT_HP, wh, wl, r, quad, mo, acc);
      }
      epilogue(acc, bsd, creg,
               p.h0p + (size_t)slotof(512 + t) * SLOT_HP + (lidx << 8),
               (t == 0) ? (p.gx + hc * BSZ) : nullptr);
      arrive(myDone, tok);
    }
    // final publish: d0>=608 for g1 dec t=95's cross gate
    if (lidx == 0) {
      sweep128(d0, 608u);
      if (tid >= 128) AST(goBF + ((tid - 128) << 4), 608u);
    }
  } else {
    // ======== group1: layer 1 ========
    load_w_lds<true>(p.we1h, p.we1l, wh, wl, hc);
    for (int t = 0; t < SEQT; ++t) {
      u32 tok = (u32)(t + 1);
      floatx4 acc = {0.f, 0.f, 0.f, 0.f};
      if (lidx == 0) {
        master_wait(d1, (u32)t, nullptr, 0u);            // own h1(t-1)
        bcast(goA, tok, goBF, (u32)t);                   // publish d1>=t to group0
      } else {
        worker_wait(myGoA, tok);
      }
      if ((t & 63) == 0 && t) fence_acq();
      kpart<true, 512, HID>(p.h1p + (size_t)slotof(t - 1) * SLOT_HP, wh, wl, r, quad, mo, acc);
      worker_wait(myGoB, (u32)(t + 1));                  // cross: d0>=t+1 (g0-master publish)
      kpart<true, 0, HID>(p.h0p + (size_t)slotof(t) * SLOT_HP, wh, wl, r, quad, mo, acc);
      epilogue(acc, bse, creg,
               p.h1p + (size_t)slotof(t) * SLOT_HP + (lidx << 8), nullptr);
      arrive(myDone, tok);
    }
    load_w_lds<true>(p.wd1h, p.wd1l, wh, wl, hc);
    for (int t = 0; t < FUTL; ++t) {
      u32 tok = (u32)(513 + t);
      floatx4 acc = {0.f, 0.f, 0.f, 0.f};
      if (lidx == 0) {
        // own h1(511+t); fcf far-lag protects h1p slot reuse for fc readers
        master_wait(d1, (u32)(512 + t), (t >= 64) ? fcf : nullptr, (u32)(t - 63));
        bcast(goA, tok, goBF, (u32)(512 + t));           // publish d1>=512+t to group0
      } else {
        worker_wait(myGoA, tok);
      }
      if ((t & 63) == 0) fence_acq();
      kpart<true, 512, HID>(p.h1p + (size_t)slotof(511 + t) * SLOT_HP, wh, wl, r, quad, mo, acc);
      worker_wait(myGoB, (u32)(513 + t));                // cross: d0>=513+t
      kpart<true, 0, HID>(p.h0p + (size_t)slotof(512 + t) * SLOT_HP, wh, wl, r, quad, mo, acc);
      epilogue(acc, bsd, creg,
               p.h1p + (size_t)slotof(512 + t) * SLOT_HP + (lidx << 8), nullptr);
      arrive(myDone, tok);
    }
  }
}

// ---------------- launch ----------------
extern "C" void kernel_launch(void* const* d_in, const int* in_sizes, int n_in,
                              void* d_out, int out_size, void* d_ws, size_t ws_size,
                              hipStream_t stream) {
  (void)in_sizes; (void)n_in; (void)out_size; (void)ws_size;
  const float* in_seq = (const float*)d_in[0];
  const float* eWih0 = (const float*)d_in[1];
  const float* eWhh0 = (const float*)d_in[2];
  const float* ebih0 = (const float*)d_in[3];
  const float* ebhh0 = (const float*)d_in[4];
  const float* eWih1 = (const float*)d_in[5];
  const float* eWhh1 = (const float*)d_in[6];
  const float* ebih1 = (const float*)d_in[7];
  const float* ebhh1 = (const float*)d_in[8];
  const float* dWih0 = (const float*)d_in[9];
  const float* dWhh0 = (const float*)d_in[10];
  const float* dbih0 = (const float*)d_in[11];
  const float* dbhh0 = (const float*)d_in[12];
  const float* dWih1 = (const float*)d_in[13];
  const float* dWhh1 = (const float*)d_in[14];
  const float* dbih1 = (const float*)d_in[15];
  const float* dbhh1 = (const float*)d_in[16];
  const float* fcW  = (const float*)d_in[17];
  const float* fcb  = (const float*)d_in[18];

  char* ws = (char*)d_ws;
  u16* we0h = (u16*)(ws + OFF_WHI_E0); u16* we0l = (u16*)(ws + OFF_WLO_E0);
  u16* we1h = (u16*)(ws + OFF_WHI_E1); u16* we1l = (u16*)(ws + OFF_WLO_E1);
  u16* wd1h = (u16*)(ws + OFF_WHI_D1); u16* wd1l = (u16*)(ws + OFF_WLO_D1);
  u16* wfh  = (u16*)(ws + OFF_WFH);    u16* wfl  = (u16*)(ws + OFF_WFL);
  u16* fch  = (u16*)(ws + OFF_FCHI);   u16* fcl  = (u16*)(ws + OFF_FCLO);
  float* gx   = (float*)(ws + OFF_GX);
  float* beff = (float*)(ws + OFF_BEFF);
  u32* xp   = (u32*)(ws + OFF_XP);
  u32* h0p  = (u32*)(ws + OFF_H0P);
  u32* h1p  = (u32*)(ws + OFF_H1P);
  u32* cnt  = (u32*)(ws + OFF_CNT);

  // zero: h0/h1 slot 0 (initial state) + counter region (ws poisoned 0xAA each call)
  hipMemsetAsync(ws + OFF_H0P, 0, (size_t)SLOT_HP * 4, stream);
  hipMemsetAsync(ws + OFF_H1P, 0, (size_t)SLOT_HP * 4, stream);
  hipMemsetAsync(ws + OFF_CNT, 0, CNT_BYTES, stream);

  k_split_pair<<<512, 256, 0, stream>>>(eWih0, eWhh0, FIN, K0, we0h, we0l);
  k_split_pair<<<512, 256, 0, stream>>>(eWih1, eWhh1, HID, K1, we1h, we1l);
  k_split_pair<<<512, 256, 0, stream>>>(dWih1, dWhh1, HID, K1, wd1h, wd1l);
  k_split_flat<<<128, 256, 0, stream>>>(fcW, fch, fcl, FIN * HID);
  k_fuse<<<NG, 256, 0, stream>>>(dWih0, dWhh0, fcW, wfh, wfl);
  k_gx<<<256, 256, 0, stream>>>(dWih0, in_seq, fcb, dbih0, dbhh0, gx, beff);
  k_pack_x<<<1024, 256, 0, stream>>>(in_seq, xp);

  Params p;
  p.we0h = we0h; p.we0l = we0l; p.we1h = we1h; p.we1l = we1l;
  p.wd1h = wd1h; p.wd1l = wd1l; p.wfh = wfh; p.wfl = wfl;
  p.fch = fch; p.fcl = fcl;
  p.xp = xp; p.h0p = h0p; p.h1p = h1p;
  p.beih0 = ebih0; p.behh0 = ebhh0; p.beih1 = ebih1; p.behh1 = ebhh1;
  p.bdih1 = dbih1; p.bdhh1 = dbhh1;
  p.gx = gx; p.beff = beff;
  p.fcb = fcb;
  p.out = (float*)d_out;
  p.cnt = cnt;

  lstm_coop<<<dim3(NBLK), dim3(NTHR), 0, stream>>>(p);
}

// Round 10
// 3455.223 us; speedup vs baseline: 1.4711x; 1.2364x over previous
//
#include <hip/hip_runtime.h>
#include <stdint.h>

typedef __attribute__((ext_vector_type(8))) short short8;
typedef __attribute__((ext_vector_type(4))) float floatx4;
typedef unsigned short u16;
typedef unsigned int u32;

constexpr int BSZ = 64;     // batch
constexpr int SEQT = 512;   // encoder timesteps
constexpr int FIN = 64;     // input features F
constexpr int HID = 512;    // hidden H
constexpr int NG = 2048;    // 4*H gate rows
constexpr int FUTL = 96;    // decoder steps
constexpr int K0 = FIN + HID;   // 576
constexpr int K1 = HID + HID;   // 1024
constexpr int K0P = K0 + 8;     // padded LDS row stride for layer-0 W
constexpr int NGRP = 256;       // layer-group blocks (2 groups x 128)
constexpr int NFCB = 4;         // dedicated fc blocks (off critical path)
constexpr int NBLK = NGRP + NFCB;
constexpr int NTHR = 256;

// packed activation slabs: one slab = 4 cols x 64 batch x u32(hi|lo<<16) = 1KB
constexpr int SLOT_HP = 128 * 256;  // u32 per h slot (128 slabs)
constexpr int SLOT_XP = 16 * 256;   // u32 per x slot (16 slabs)
constexpr int NSLOT_H = 65;         // slot 0 = zeros; slot(u) = u%64+1

// ---------------- workspace layout (bytes) ----------------
constexpr size_t S_W0 = (size_t)NG * K0 * 2;
constexpr size_t S_W1 = (size_t)NG * K1 * 2;
constexpr size_t S_FC = (size_t)FIN * HID * 2;

constexpr size_t OFF_WHI_E0 = 0;
constexpr size_t OFF_WLO_E0 = OFF_WHI_E0 + S_W0;
constexpr size_t OFF_WHI_E1 = OFF_WLO_E0 + S_W0;
constexpr size_t OFF_WLO_E1 = OFF_WHI_E1 + S_W1;
constexpr size_t OFF_WHI_D1 = OFF_WLO_E1 + S_W1;
constexpr size_t OFF_WLO_D1 = OFF_WHI_D1 + S_W1;
constexpr size_t OFF_WFH   = OFF_WLO_D1 + S_W1;  // fused dec-L0 [2048][1024] = [Wih0d@fcW | Whh0d]
constexpr size_t OFF_WFL   = OFF_WFH + S_W1;
constexpr size_t OFF_FCHI  = OFF_WFL + S_W1;
constexpr size_t OFF_FCLO  = OFF_FCHI + S_FC;
constexpr size_t OFF_GX    = OFF_FCLO + S_FC;               // [2048][64] f32: Wih0d@(x_last - fcb)
constexpr size_t OFF_BEFF  = OFF_GX + (size_t)NG * BSZ * 4; // [2048] f32: bdih0+bdhh0+Wih0d@fcb
constexpr size_t OFF_XP    = OFF_BEFF + (size_t)NG * 4;     // 512 slots
constexpr size_t OFF_H0P   = OFF_XP + (size_t)SEQT * SLOT_XP * 4;
constexpr size_t OFF_H1P   = OFF_H0P + (size_t)NSLOT_H * SLOT_HP * 4;
constexpr size_t OFF_CNT   = OFF_H1P + (size_t)NSLOT_H * SLOT_HP * 4;
constexpr size_t CNT_BYTES = 65536;

// cnt layout (u32 idx): fcdone @0 (4 cells x16); done0 @256 (128x16); done1 @2304;
// goA0 @4352; goB0 @6400; goA1 @8448; goB1 @10496.
// goA*: own-master "stage go" broadcast. goB*: FOREIGN master's progress broadcast.
#define FCF(c)   ((c) + 0)
#define DONE0(c) ((c) + 256)
#define DONE1(c) ((c) + 2304)
#define GOA0(c)  ((c) + 4352)
#define GOB0(c)  ((c) + 6400)
#define GOA1(c)  ((c) + 8448)
#define GOB1(c)  ((c) + 10496)

// ---------------- bf16 helpers ----------------
__device__ __forceinline__ u16 f2bf(float f) {
  u32 u = __float_as_uint(f);
  u += 0x7FFFu + ((u >> 16) & 1u);   // RNE
  return (u16)(u >> 16);
}
__device__ __forceinline__ float bf2f(u16 h) { return __uint_as_float(((u32)h) << 16); }
__device__ __forceinline__ u32 packsplit(float v) {
  u16 h = f2bf(v);
  u16 l = f2bf(v - bf2f(h));
  return (u32)h | ((u32)l << 16);
}

__device__ __forceinline__ float sigf(float x) { return 1.f / (1.f + __expf(-x)); }
__device__ __forceinline__ float tanh_f(float x) {
  float xx = fminf(20.f, fmaxf(-20.f, x));
  float e = __expf(-2.f * xx);
  return (1.f - e) / (1.f + e);
}

__device__ __forceinline__ floatx4 mfma3(short8 ah, short8 al, short8 bh, short8 bl, floatx4 acc) {
  acc = __builtin_amdgcn_mfma_f32_16x16x32_bf16(ah, bh, acc, 0, 0, 0);
  acc = __builtin_amdgcn_mfma_f32_16x16x32_bf16(ah, bl, acc, 0, 0, 0);
  acc = __builtin_amdgcn_mfma_f32_16x16x32_bf16(al, bh, acc, 0, 0, 0);
  return acc;
}

// write-through store: lands at the coherent point; no release fence needed.
__device__ __forceinline__ void st_sc_u32(u32* p, u32 v) {
  asm volatile("global_store_dword %0, %1, off sc0 sc1" :: "v"(p), "v"(v) : "memory");
}
#define WAITVM0() asm volatile("s_waitcnt vmcnt(0)" ::: "memory")

#define ALD(p) __hip_atomic_load((p), __ATOMIC_RELAXED, __HIP_MEMORY_SCOPE_AGENT)
#define AST(p, v) __hip_atomic_store((p), (v), __ATOMIC_RELAXED, __HIP_MEMORY_SCOPE_AGENT)

__device__ __forceinline__ int slotof(int u) { return u < 0 ? 0 : ((u & 63) + 1); }

// packed A-fragment load: 8 cols (2 slabs) for batch row m -> hi/lo short8 (cached loads)
__device__ __forceinline__ void ld_frag(const u32* p, short8& ah, short8& al) {
  uint4 a = *(const uint4*)p;
  uint4 b = *(const uint4*)(p + 256);
  union { u32 u[4]; short8 s; } H, L;
  H.u[0] = __builtin_amdgcn_perm(a.y, a.x, 0x05040100u);
  L.u[0] = __builtin_amdgcn_perm(a.y, a.x, 0x07060302u);
  H.u[1] = __builtin_amdgcn_perm(a.w, a.z, 0x05040100u);
  L.u[1] = __builtin_amdgcn_perm(a.w, a.z, 0x07060302u);
  H.u[2] = __builtin_amdgcn_perm(b.y, b.x, 0x05040100u);
  L.u[2] = __builtin_amdgcn_perm(b.y, b.x, 0x07060302u);
  H.u[3] = __builtin_amdgcn_perm(b.w, b.z, 0x05040100u);
  L.u[3] = __builtin_amdgcn_perm(b.w, b.z, 0x07060302u);
  ah = H.s; al = L.s;
}

// ---------------- prep kernels ----------------
__global__ void k_split_pair(const float* __restrict__ Wih, const float* __restrict__ Whh,
                             int ins, int K, u16* __restrict__ hi, u16* __restrict__ lo) {
  int n = NG * K;
  for (int idx = blockIdx.x * blockDim.x + threadIdx.x; idx < n; idx += gridDim.x * blockDim.x) {
    int row = idx / K;
    int k = idx - row * K;
    float v = (k < ins) ? Wih[row * ins + k] : Whh[row * HID + (k - ins)];
    u16 h = f2bf(v);
    hi[idx] = h;
    lo[idx] = f2bf(v - bf2f(h));
  }
}

__global__ void k_split_flat(const float* __restrict__ src, u16* __restrict__ hi,
                             u16* __restrict__ lo, int n) {
  for (int idx = blockIdx.x * blockDim.x + threadIdx.x; idx < n; idx += gridDim.x * blockDim.x) {
    float v = src[idx];
    u16 h = f2bf(v);
    hi[idx] = h;
    lo[idx] = f2bf(v - bf2f(h));
  }
}

// fused decoder-L0 weights: cols [0,512) = Wih0d @ fcW, cols [512,1024) = Whh0d
__global__ void k_fuse(const float* __restrict__ dWih0, const float* __restrict__ dWhh0,
                       const float* __restrict__ fcW,
                       u16* __restrict__ wfh, u16* __restrict__ wfl) {
  __shared__ float wr[FIN];
  const int row = blockIdx.x;            // gate row 0..2047
  if (threadIdx.x < FIN) wr[threadIdx.x] = dWih0[row * FIN + threadIdx.x];
  __syncthreads();
  for (int j = threadIdx.x; j < HID; j += blockDim.x) {
    float acc = 0.f;
#pragma unroll
    for (int f = 0; f < FIN; ++f) acc = fmaf(wr[f], fcW[f * HID + j], acc);
    u16 h = f2bf(acc);
    wfh[(size_t)row * K1 + j] = h;
    wfl[(size_t)row * K1 + j] = f2bf(acc - bf2f(h));
    float v2 = dWhh0[row * HID + j];
    u16 h2 = f2bf(v2);
    wfh[(size_t)row * K1 + HID + j] = h2;
    wfl[(size_t)row * K1 + HID + j] = f2bf(v2 - bf2f(h2));
  }
}

// gx[row][b] = Wih0d @ (x_last[b] - fcb);  beff[row] = bdih0+bdhh0+Wih0d@fcb
__global__ void k_gx(const float* __restrict__ dWih0, const float* __restrict__ in_seq,
                     const float* __restrict__ fcb, const float* __restrict__ bdih0,
                     const float* __restrict__ bdhh0, float* __restrict__ gx,
                     float* __restrict__ beff) {
  __shared__ float xl[BSZ * FIN];
  __shared__ float fb[FIN];
  const int row0 = blockIdx.x * 8;       // 256 blocks x 8 rows
  for (int i = threadIdx.x; i < BSZ * FIN; i += blockDim.x) {
    int b = i >> 6, f = i & 63;
    xl[i] = in_seq[(b * SEQT + (SEQT - 1)) * FIN + f];
  }
  if (threadIdx.x < FIN) fb[threadIdx.x] = fcb[threadIdx.x];
  __syncthreads();
  for (int i = threadIdx.x; i < 8 * BSZ; i += blockDim.x) {
    int r = row0 + (i >> 6);
    int b = i & 63;
    float acc = 0.f;
#pragma unroll 8
    for (int f = 0; f < FIN; ++f)
      acc = fmaf(dWih0[r * FIN + f], xl[(b << 6) + f] - fb[f], acc);
    gx[r * BSZ + b] = acc;
    if (b == 0) {
      float accb = 0.f;
#pragma unroll 8
      for (int f = 0; f < FIN; ++f) accb = fmaf(dWih0[r * FIN + f], fb[f], accb);
      beff[r] = bdih0[r] + bdhh0[r] + accb;
    }
  }
}

// input_seq [B][T][F] -> packed slabs xp[t][kb][m][j]
__global__ void k_pack_x(const float* __restrict__ x, u32* __restrict__ xp) {
  int n = BSZ * SEQT * FIN;
  for (int idx = blockIdx.x * blockDim.x + threadIdx.x; idx < n; idx += gridDim.x * blockDim.x) {
    int t = idx / (BSZ * FIN);
    int rem = idx - t * (BSZ * FIN);
    int b = rem >> 6;
    int f = rem & 63;
    u32 pk = packsplit(x[(b * SEQT + t) * FIN + f]);
    int off = ((f >> 2) * 64 + b) * 4 + (f & 3);
    xp[t * SLOT_XP + off] = pk;
  }
}

// ---------------- params ----------------
struct Params {
  const u16 *we0h, *we0l, *we1h, *we1l;
  const u16 *wd1h, *wd1l, *wfh, *wfl;
  const u16 *fch, *fcl;
  const u32 *xp;
  u32 *h0p, *h1p;
  const float *beih0, *behh0, *beih1, *behh1;
  const float *bdih1, *bdhh1;
  const float *gx, *beff;
  const float *fcb;
  float *out;
  u32 *cnt;
};

// ---------------- sync ----------------
// Master sweep: wave0 checks 128 own cells (2/lane). No sleep: observe ASAP.
__device__ void master_wait(u32* own, u32 ownT) {
  if (threadIdx.x < 64) {
    int l = threadIdx.x;
    while (!__all(ALD(own + l * 16) >= ownT && ALD(own + (l + 64) * 16) >= ownT)) {}
  }
  __syncthreads();
}

// sweep of a 128-cell done array (fc blocks + transitions; keep sleep, off critical path)
__device__ void sweep128(u32* arr, u32 T) {
  if (threadIdx.x < 64) {
    int l = threadIdx.x;
    while (!__all(ALD(arr + l * 16) >= T && ALD(arr + (l + 64) * 16) >= T))
      __builtin_amdgcn_s_sleep(1);
  }
  __syncthreads();
}

// Single-cell wait: 1 poller per line (proven shape; barrier-free variants hung).
__device__ __forceinline__ void worker_wait(u32* cell, u32 tok) {
  if (threadIdx.x == 0) {
    while (ALD(cell) < tok) {}
  }
  __syncthreads();
}

// Cached single-cell wait on a MONOTONE progress value: skip the MALL RTT when a
// previously observed value already proves the predicate.
__device__ __forceinline__ void worker_wait_c(u32* cell, u32 tok, u32& cache) {
  if (threadIdx.x == 0 && cache < tok) {
    u32 v;
    do { v = ALD(cell); } while (v < tok);
    cache = v;
  }
  __syncthreads();
}

// fcf (4 cells) cached min-wait
__device__ __forceinline__ void fcf_wait_c(u32* fcf, u32 tok, u32& cache) {
  if (threadIdx.x == 0 && cache < tok) {
    u32 m;
    do {
      u32 a = ALD(fcf), b = ALD(fcf + 16), c = ALD(fcf + 32), d = ALD(fcf + 48);
      u32 m1 = a < b ? a : b, m2 = c < d ? c : d;
      m = m1 < m2 ? m1 : m2;
    } while (m < tok);
    cache = m;
  }
  __syncthreads();
}

__device__ __forceinline__ void fence_acq() {
  __builtin_amdgcn_fence(__ATOMIC_ACQUIRE, "agent");   // epoch boundary only
}

// Arrival: drain own sc stores (each wave), then one token store to this block's cell.
__device__ __forceinline__ void arrive(u32* cell, u32 tok) {
  WAITVM0();
  __syncthreads();
  if (threadIdx.x == 0) AST(cell, tok);
}

// Master dual broadcast: tids 1..127 -> own group's goA cells (stage token);
// tids 128..255 -> FOREIGN group's goB cells (own-done progress value).
__device__ __forceinline__ void bcast(u32* goA, u32 tokA, u32* goBF, u32 prog) {
  const int tid = threadIdx.x;
  if (tid >= 1 && tid < 128) AST(goA + (tid << 4), tokA);
  else if (tid >= 128) AST(goBF + ((tid - 128) << 4), prog);
}

// ---------------- W -> LDS (persistent) ----------------
template <bool IS_L1>
__device__ void load_w_lds(const u16* __restrict__ gh, const u16* __restrict__ gl,
                           u16* wh, u16* wl, int hc) {
  constexpr int K = IS_L1 ? K1 : K0;
  for (int i = threadIdx.x; i < 16 * K; i += NTHR) {
    int rr, k;
    if (IS_L1) { rr = i >> 10; k = i & 1023; }
    else       { rr = i / K0;  k = i - rr * K0; }
    int gc = ((rr >> 2) * HID) + hc + (rr & 3);   // row r -> gate q=r>>2, col j=r&3
    int dst = IS_L1 ? ((rr << 10) + ((((k >> 3) ^ rr)) << 3) + (k & 7))
                    : (rr * K0P + k);
    wh[dst] = gh[(size_t)gc * K + k];
    wl[dst] = gl[(size_t)gc * K + k];
  }
  __syncthreads();
}

// ---------------- K-range partial GEMM: acc += W[:, KBASE:KBASE+LEN] @ slab --------------
// r5 form (measured best): compiler pipelines loads under MFMAs.
template <bool IS_L1, int KBASE, int LEN>
__device__ __forceinline__ void kpart(const u32* __restrict__ sp,
                                      const u16* __restrict__ wh, const u16* __restrict__ wl,
                                      int r, int quad, int mo, floatx4& acc) {
  const int qo = quad << 3;
  constexpr int NIT = LEN / 32;
  uint4 ra[NIT], rb[NIT];
#pragma unroll
  for (int i = 0; i < NIT; ++i) {
    const u32* p = sp + (((i * 32 + qo) >> 2) << 8) + mo;
    ra[i] = *(const uint4*)p;
    rb[i] = *(const uint4*)(p + 256);
  }
#pragma unroll
  for (int i = 0; i < NIT; ++i) {
    union { u32 u[4]; short8 s; } H, L;
    H.u[0] = __builtin_amdgcn_perm(ra[i].y, ra[i].x, 0x05040100u);
    L.u[0] = __builtin_amdgcn_perm(ra[i].y, ra[i].x, 0x07060302u);
    H.u[1] = __builtin_amdgcn_perm(ra[i].w, ra[i].z, 0x05040100u);
    L.u[1] = __builtin_amdgcn_perm(ra[i].w, ra[i].z, 0x07060302u);
    H.u[2] = __builtin_amdgcn_perm(rb[i].y, rb[i].x, 0x05040100u);
    L.u[2] = __builtin_amdgcn_perm(rb[i].y, rb[i].x, 0x07060302u);
    H.u[3] = __builtin_amdgcn_perm(rb[i].w, rb[i].z, 0x05040100u);
    L.u[3] = __builtin_amdgcn_perm(rb[i].w, rb[i].z, 0x07060302u);
    const int kg = i * 32 + KBASE;
    int woff;
    if (IS_L1) { int c = (kg >> 3) + quad; woff = (r << 10) + ((c ^ r) << 3); }
    else       { woff = r * K0P + kg + qo; }
    short8 bh = *(const short8*)(wh + woff);
    short8 bl = *(const short8*)(wl + woff);
    acc = mfma3(H.s, L.s, bh, bl, acc);
  }
}

// ---------------- epilogue: gates -> (h,c), packed write-through store ----------------
__device__ __forceinline__ void epilogue(floatx4 acc, floatx4 bs, float& creg,
                                         u32* __restrict__ oslab,
                                         const float* __restrict__ gxb) {
  const int tid = threadIdx.x, lane = tid & 63;
  const int j = lane & 3;
  const int isel = (lane >> 2) & 3;
  const int slb = lane & 48;
  float gate[4];
#pragma unroll
  for (int q = 0; q < 4; ++q) {
    const int sl = slb + (q << 2) + j;
    float t0 = __shfl(acc[0], sl, 64);
    float t1 = __shfl(acc[1], sl, 64);
    float t2 = __shfl(acc[2], sl, 64);
    float t3 = __shfl(acc[3], sl, 64);
    gate[q] = (isel == 0) ? t0 : (isel == 1) ? t1 : (isel == 2) ? t2 : t3;
  }
  if (gxb != nullptr) {
    const int bb = tid >> 2;
#pragma unroll
    for (int q = 0; q < 4; ++q) gate[q] += gxb[q * (HID * BSZ) + j * BSZ + bb];
  }
  float iv = gate[0] + bs[0];
  float fv = gate[1] + bs[1];
  float gv = gate[2] + bs[2];
  float ov = gate[3] + bs[3];
  float cn = fmaf(sigf(fv), creg, sigf(iv) * tanh_f(gv));
  float hn = sigf(ov) * tanh_f(cn);
  creg = cn;
  st_sc_u32(oslab + tid, packsplit(hn));   // wave-contiguous 256B write-through
}

// ---------------- decoder fc (dedicated blocks): out = dh1 @ fcW^T + fcb ----------------
__device__ void fc_step(int t, int blkq, const u32* __restrict__ h1slot,
                        const u16* __restrict__ fh, const u16* __restrict__ fl,
                        const float* __restrict__ fcb, float* __restrict__ out) {
  const int tid = threadIdx.x, lane = tid & 63, w = tid >> 6;
  const int quad = lane >> 4, r = lane & 15;
  const int m = (w << 4) + r;
  const int qo = quad << 3;
  const int mo = m << 2;
  const int col = (blkq << 4) + r;
  floatx4 acc = {0.f, 0.f, 0.f, 0.f};
#pragma unroll
  for (int kk = 0; kk < HID; kk += 32) {
    short8 ah, al;
    ld_frag(h1slot + (((kk + qo) >> 2) << 8) + mo, ah, al);
    short8 b1 = *(const short8*)(fh + col * HID + kk + qo);
    short8 b2 = *(const short8*)(fl + col * HID + kk + qo);
    acc = mfma3(ah, al, b1, b2, acc);
  }
  float bias = fcb[col];
#pragma unroll
  for (int i = 0; i < 4; ++i) {
    int b = (w << 4) + (quad << 2) + i;
    out[(b * FUTL + t) * FIN + col] = acc[i] + bias;
  }
}

// ---------------- the persistent kernel ----------------
__global__ __launch_bounds__(NTHR, 1) void lstm_coop(Params p) {
  __shared__ u16 wsmem[32768];              // 64 KB: hi at [0], lo at [16K]
  u16* wh = wsmem;
  u16* wl = wsmem + 16 * 1024;
  const int blk = blockIdx.x;
  const int tid = threadIdx.x;

  u32* fcf = FCF(p.cnt);
  u32* d0 = DONE0(p.cnt);
  u32* d1 = DONE1(p.cnt);

  if (blk >= NGRP) {
    // ======== dedicated fc blocks: consume h1-dec(t), produce out (off critical path) ====
    const int fi = blk - NGRP;              // 0..3, 16 out-cols each
    for (int t = 0; t < FUTL; ++t) {
      sweep128(d1, (u32)(513 + t));         // h1-dec(t) ready
      if ((t & 63) == 0) fence_acq();       // epoch boundary: recycled h1p lines
      fc_step(t, fi, p.h1p + (size_t)slotof(512 + t) * SLOT_HP,
              p.fch, p.fcl, p.fcb, p.out);
      WAITVM0();
      __syncthreads();
      if (tid == 0) AST(fcf + fi * 16, (u32)(t + 1));  // slot-protection token only
    }
    return;
  }

  const int grp = blk >> 7;
  const int lidx = blk & 127;
  const int hc = lidx << 2;
  const int lane = tid & 63, w = tid >> 6;
  const int quad = lane >> 4, r = lane & 15;
  const int mo = ((w << 4) + r) << 2;

  u32* goA  = grp ? GOA1(p.cnt) : GOA0(p.cnt);
  u32* goBF = grp ? GOB0(p.cnt) : GOB1(p.cnt);   // FOREIGN group's progress cells (master writes)
  u32* myGoA = goA + lidx * 16;
  u32* myGoB = (grp ? GOB1(p.cnt) : GOB0(p.cnt)) + lidx * 16;  // own cell, foreign master writes
  u32* myDone = (grp ? d1 : d0) + lidx * 16;

  floatx4 bse, bsd;
  {
    int ch = hc + (tid & 3);
    const float* bi  = grp ? p.beih1 : p.beih0;
    const float* bh2 = grp ? p.behh1 : p.behh0;
#pragma unroll
    for (int q = 0; q < 4; ++q) {
      bse[q] = bi[q * HID + ch] + bh2[q * HID + ch];
      bsd[q] = grp ? (p.bdih1[q * HID + ch] + p.bdhh1[q * HID + ch])
                   : p.beff[q * HID + ch];   // dec-L0 bias has Wih0d@fcb folded in
    }
  }
  float creg = 0.f;

  if (!grp) {
    // ======== group0: layer 0 ========
    u32 d1seen = 0;   // cached g1-progress (myGoB, monotone)
    load_w_lds<false>(p.we0h, p.we0l, wh, wl, hc);
    for (int s = 0; s < SEQT; ++s) {
      u32 tok = (u32)(s + 1);
      floatx4 acc = {0.f, 0.f, 0.f, 0.f};
      if (lidx == 0) {
        master_wait(d0, (u32)s);                          // own recurrence gate
        if (s >= 63) worker_wait_c(myGoB, (u32)(s - 63), d1seen);  // far-lag (cached skip)
        bcast(goA, tok, goBF, (u32)s);                    // goA + publish d0>=s to group1
        if ((s & 63) == 0 && s) fence_acq();
        kpart<false, 0, FIN>(p.xp + (size_t)s * SLOT_XP, wh, wl, r, quad, mo, acc);
      } else {
        // x-part has no cross-step dependency: compute it while waiting
        kpart<false, 0, FIN>(p.xp + (size_t)s * SLOT_XP, wh, wl, r, quad, mo, acc);
        worker_wait(myGoA, tok);
        if ((s & 63) == 0 && s) fence_acq();
      }
      kpart<false, FIN, HID>(p.h0p + (size_t)slotof(s - 1) * SLOT_HP, wh, wl, r, quad, mo, acc);
      epilogue(acc, bse, creg,
               p.h0p + (size_t)slotof(s) * SLOT_HP + (lidx << 8), nullptr);
      arrive(myDone, tok);
    }
    // transition: publish d0>=512 BEFORE the dec weight load (g1 enc s=511 needs it)
    if (lidx == 0) {
      sweep128(d0, 512u);
      if (tid >= 128) AST(goBF + ((tid - 128) << 4), 512u);
    }
    // decoder: fused weights [Weff | Whh0d], K=1024, layer-1-shaped step.
    load_w_lds<true>(p.wfh, p.wfl, wh, wl, hc);
    for (int t = 0; t < FUTL; ++t) {
      u32 tok = (u32)(513 + t);
      floatx4 acc = {0.f, 0.f, 0.f, 0.f};
      if (lidx == 0) {
        master_wait(d0, (u32)(512 + t));                  // own h0(511+t)
        if (t == 0) worker_wait_c(myGoB, 449u, d1seen);   // slot-1 overwrite gate
        bcast(goA, tok, goBF, (u32)(512 + t));
      } else {
        worker_wait(myGoA, tok);
      }
      if ((t & 63) == 0) fence_acq();        // u=512, 576 epoch boundaries
      kpart<true, 512, HID>(p.h0p + (size_t)slotof(511 + t) * SLOT_HP, wh, wl, r, quad, mo, acc);
      if (t) {
        // cross: h1(511+t) feeds the fused Weff part; g1-master published d1>=512+t
        worker_wait_c(myGoB, (u32)(512 + t), d1seen);
        kpart<true, 0, HID>(p.h1p + (size_t)slotof(511 + t) * SLOT_HP, wh, wl, r, quad, mo, acc);
      }
      epilogue(acc, bsd, creg,
               p.h0p + (size_t)slotof(512 + t) * SLOT_HP + (lidx << 8),
               (t == 0) ? (p.gx + hc * BSZ) : nullptr);
      arrive(myDone, tok);
    }
    // final publish: d0>=608 for g1 dec t=95's cross gate
    if (lidx == 0) {
      sweep128(d0, 608u);
      if (tid >= 128) AST(goBF + ((tid - 128) << 4), 608u);
    }
  } else {
    // ======== group1: layer 1 ========
    u32 d0seen = 0;   // cached g0-progress (myGoB, monotone)
    u32 fcseen = 0;   // cached fc progress (master only)
    load_w_lds<true>(p.we1h, p.we1l, wh, wl, hc);
    for (int t = 0; t < SEQT; ++t) {
      u32 tok = (u32)(t + 1);
      floatx4 acc = {0.f, 0.f, 0.f, 0.f};
      // CROSS-FIRST: g1 lags g0 in steady state, so the cross gate (d0>=t+1) is
      // pre-published (cached). Doing the cross kpart first overlaps the own-gate
      // chain (sweep+bcast+observe) with real compute. [acc order: cross then own]
      if (lidx == 0) {
        master_wait(d1, (u32)t);                          // own gate (master role)
        bcast(goA, tok, goBF, (u32)t);                    // release + publish d1>=t to g0
        worker_wait_c(myGoB, (u32)(t + 1), d0seen);       // cross gate
        if ((t & 63) == 0 && t) fence_acq();
        kpart<true, 0, HID>(p.h0p + (size_t)slotof(t) * SLOT_HP, wh, wl, r, quad, mo, acc);
        kpart<true, 512, HID>(p.h1p + (size_t)slotof(t - 1) * SLOT_HP, wh, wl, r, quad, mo, acc);
      } else {
        worker_wait_c(myGoB, (u32)(t + 1), d0seen);       // cross gate (usually cached)
        if ((t & 63) == 0 && t) fence_acq();
        kpart<true, 0, HID>(p.h0p + (size_t)slotof(t) * SLOT_HP, wh, wl, r, quad, mo, acc);
        worker_wait(myGoA, tok);                          // own gate (arrived during cross)
        kpart<true, 512, HID>(p.h1p + (size_t)slotof(t - 1) * SLOT_HP, wh, wl, r, quad, mo, acc);
      }
      epilogue(acc, bse, creg,
               p.h1p + (size_t)slotof(t) * SLOT_HP + (lidx << 8), nullptr);
      arrive(myDone, tok);
    }
    load_w_lds<true>(p.wd1h, p.wd1l, wh, wl, hc);
    for (int t = 0; t < FUTL; ++t) {
      u32 tok = (u32)(513 + t);
      floatx4 acc = {0.f, 0.f, 0.f, 0.f};
      if (lidx == 0) {
        master_wait(d1, (u32)(512 + t));                  // own h1(511+t)
        if (t >= 64) fcf_wait_c(fcf, (u32)(t - 63), fcseen);  // h1p slot reuse vs fc readers
        bcast(goA, tok, goBF, (u32)(512 + t));            // publish d1>=512+t to group0
      } else {
        worker_wait(myGoA, tok);
      }
      if ((t & 63) == 0) fence_acq();
      kpart<true, 512, HID>(p.h1p + (size_t)slotof(511 + t) * SLOT_HP, wh, wl, r, quad, mo, acc);
      worker_wait_c(myGoB, (u32)(513 + t), d0seen);       // cross: d0>=513+t
      kpart<true, 0, HID>(p.h0p + (size_t)slotof(512 + t) * SLOT_HP, wh, wl, r, quad, mo, acc);
      epilogue(acc, bsd, creg,
               p.h1p + (size_t)slotof(512 + t) * SLOT_HP + (lidx << 8), nullptr);
      arrive(myDone, tok);
    }
  }
}

// ---------------- launch ----------------
extern "C" void kernel_launch(void* const* d_in, const int* in_sizes, int n_in,
                              void* d_out, int out_size, void* d_ws, size_t ws_size,
                              hipStream_t stream) {
  (void)in_sizes; (void)n_in; (void)out_size; (void)ws_size;
  const float* in_seq = (const float*)d_in[0];
  const float* eWih0 = (const float*)d_in[1];
  const float* eWhh0 = (const float*)d_in[2];
  const float* ebih0 = (const float*)d_in[3];
  const float* ebhh0 = (const float*)d_in[4];
  const float* eWih1 = (const float*)d_in[5];
  const float* eWhh1 = (const float*)d_in[6];
  const float* ebih1 = (const float*)d_in[7];
  const float* ebhh1 = (const float*)d_in[8];
  const float* dWih0 = (const float*)d_in[9];
  const float* dWhh0 = (const float*)d_in[10];
  const float* dbih0 = (const float*)d_in[11];
  const float* dbhh0 = (const float*)d_in[12];
  const float* dWih1 = (const float*)d_in[13];
  const float* dWhh1 = (const float*)d_in[14];
  const float* dbih1 = (const float*)d_in[15];
  const float* dbhh1 = (const float*)d_in[16];
  const float* fcW  = (const float*)d_in[17];
  const float* fcb  = (const float*)d_in[18];

  char* ws = (char*)d_ws;
  u16* we0h = (u16*)(ws + OFF_WHI_E0); u16* we0l = (u16*)(ws + OFF_WLO_E0);
  u16* we1h = (u16*)(ws + OFF_WHI_E1); u16* we1l = (u16*)(ws + OFF_WLO_E1);
  u16* wd1h = (u16*)(ws + OFF_WHI_D1); u16* wd1l = (u16*)(ws + OFF_WLO_D1);
  u16* wfh  = (u16*)(ws + OFF_WFH);    u16* wfl  = (u16*)(ws + OFF_WFL);
  u16* fch  = (u16*)(ws + OFF_FCHI);   u16* fcl  = (u16*)(ws + OFF_FCLO);
  float* gx   = (float*)(ws + OFF_GX);
  float* beff = (float*)(ws + OFF_BEFF);
  u32* xp   = (u32*)(ws + OFF_XP);
  u32* h0p  = (u32*)(ws + OFF_H0P);
  u32* h1p  = (u32*)(ws + OFF_H1P);
  u32* cnt  = (u32*)(ws + OFF_CNT);

  // zero: h0/h1 slot 0 (initial state) + counter region (ws poisoned 0xAA each call)
  hipMemsetAsync(ws + OFF_H0P, 0, (size_t)SLOT_HP * 4, stream);
  hipMemsetAsync(ws + OFF_H1P, 0, (size_t)SLOT_HP * 4, stream);
  hipMemsetAsync(ws + OFF_CNT, 0, CNT_BYTES, stream);

  k_split_pair<<<512, 256, 0, stream>>>(eWih0, eWhh0, FIN, K0, we0h, we0l);
  k_split_pair<<<512, 256, 0, stream>>>(eWih1, eWhh1, HID, K1, we1h, we1l);
  k_split_pair<<<512, 256, 0, stream>>>(dWih1, dWhh1, HID, K1, wd1h, wd1l);
  k_split_flat<<<128, 256, 0, stream>>>(fcW, fch, fcl, FIN * HID);
  k_fuse<<<NG, 256, 0, stream>>>(dWih0, dWhh0, fcW, wfh, wfl);
  k_gx<<<256, 256, 0, stream>>>(dWih0, in_seq, fcb, dbih0, dbhh0, gx, beff);
  k_pack_x<<<1024, 256, 0, stream>>>(in_seq, xp);

  Params p;
  p.we0h = we0h; p.we0l = we0l; p.we1h = we1h; p.we1l = we1l;
  p.wd1h = wd1h; p.wd1l = wd1l; p.wfh = wfh; p.wfl = wfl;
  p.fch = fch; p.fcl = fcl;
  p.xp = xp; p.h0p = h0p; p.h1p = h1p;
  p.beih0 = ebih0; p.behh0 = ebhh0; p.beih1 = ebih1; p.behh1 = ebhh1;
  p.bdih1 = dbih1; p.bdhh1 = dbhh1;
  p.gx = gx; p.beff = beff;
  p.fcb = fcb;
  p.out = (float*)d_out;
  p.cnt = cnt;

  lstm_coop<<<dim3(NBLK), dim3(NTHR), 0, stream>>>(p);
}